// Round 9
// baseline (119.650 us; speedup 1.0000x reference)
//
#include <hip/hip_runtime.h>
#include <math.h>

typedef __attribute__((ext_vector_type(8))) short short8;
typedef __attribute__((ext_vector_type(4))) float floatx4;

#define NH 4
#define HD 32
#define DIM 128
#define SEQ 256
#define BATCH 128
#define BS (BATCH*SEQ)
#define RANK 8
#define SCALING 2.0f
#define INV_SQRT_HD 0.17677669529663687f
#define LOG2E 1.4426950408889634f

#if __has_builtin(__builtin_amdgcn_exp2f)
#define EXP2F __builtin_amdgcn_exp2f
#else
#define EXP2F exp2f
#endif

// workspace byte offsets
#define KB_OFF  (8ull<<20)
#define VT_OFF  (16ull<<20)   // V fragment-linear (b,h,chunk,parity), kappa-permuted keys
#define XB_OFF  (24ull<<20)   // x bf16, fragment-linear
#define WE_OFF  (32ull<<20)   // 4 x 128x128 bf16 weights, fragment-linear
#define TAB_OFF (33ull<<20)   // 256x16 float2 (cos,sin)

static __device__ __forceinline__ unsigned short f2bf(float f) {
    unsigned u = __float_as_uint(f);
    return (unsigned short)((u + 0x7FFFu + ((u >> 16) & 1u)) >> 16);
}
// RNE bf16 pair pack: 2 add-chains + 1 v_perm_b32
static __device__ __forceinline__ unsigned packbf(float lo, float hi) {
    unsigned ua = __float_as_uint(lo), ub = __float_as_uint(hi);
    ua += 0x7FFFu + ((ua >> 16) & 1u);
    ub += 0x7FFFu + ((ub >> 16) & 1u);
    return __builtin_amdgcn_perm(ub, ua, 0x07060302);  // (hi16(ub)<<16)|hi16(ua)
}

// ---------------------------------------------------------------------------
// prep: fragment-linear weights (LoRA folded; q gets 1/sqrt(hd)*log2e),
// RoPE table, x -> bf16 fragment-linear.  grid = 128 + 16 + 2048.
// ---------------------------------------------------------------------------
__global__ __launch_bounds__(256) void prep_kernel(
    const float* __restrict__ x,
    const float* __restrict__ wq, const float* __restrict__ wk,
    const float* __restrict__ wv, const float* __restrict__ wo,
    const float* __restrict__ Aq, const float* __restrict__ Bq,
    const float* __restrict__ Ak, const float* __restrict__ Bk,
    const float* __restrict__ Av, const float* __restrict__ Bv,
    unsigned short* __restrict__ weffL, float* __restrict__ tab,
    unsigned short* __restrict__ xbL)
{
    const int bid = blockIdx.x, tid = threadIdx.x;
    if (bid < 128) {
        int t = bid * 256 + tid;            // u32 index 0..32767
        int m    = t >> 13;
        int kc   = (t >> 11) & 3;
        int s    = (t >> 8) & 7;
        int lane = (t >> 2) & 63;
        int e    = t & 3;                   // u32 within fragment
        int m16 = lane & 15, quad = lane >> 4;
        int row = (m < 3) ? ((s >> 1) * 32 + 2 * m16 + (s & 1)) : (s * 16 + m16);
        int col = kc * 32 + quad * 8 + 2 * e;
        const float* W = m == 0 ? wq : (m == 1 ? wk : (m == 2 ? wv : wo));
        const float* A  = m == 0 ? Aq : (m == 1 ? Ak : Av);
        const float* Bm = m == 0 ? Bq : (m == 1 ? Bk : Bv);
        float v0 = W[row * DIM + col], v1 = W[row * DIM + col + 1];
        if (m < 3) {
            float s0 = 0.f, s1 = 0.f;
#pragma unroll
            for (int r = 0; r < RANK; r++) {
                float br = Bm[row * RANK + r];
                s0 += br * A[r * DIM + col];
                s1 += br * A[r * DIM + col + 1];
            }
            v0 += SCALING * s0;
            v1 += SCALING * s1;
        }
        if (m == 0) { v0 *= INV_SQRT_HD * LOG2E; v1 *= INV_SQRT_HD * LOG2E; }
        ((unsigned*)weffL)[t] = packbf(v0, v1);
    } else if (bid < 144) {
        int gid = (bid - 128) * 256 + tid;  // 0..4095
        int spos = gid >> 4, i = gid & 15;
        float invf = exp2f(-0.83048202f * (float)i);  // 10000^(-i/16)
        float ang = (float)spos * invf;
        float c, s;
        sincosf(ang, &s, &c);
        tab[gid * 2]     = c;
        tab[gid * 2 + 1] = s;
    } else {
        int t = (bid - 144) * 256 + tid;    // 0..524287
        int g    = t >> 8;
        int kc   = (t >> 6) & 3;
        int lane = t & 63;
        int m16 = lane & 15, quad = lane >> 4;
        const float* xp = x + (size_t)(g * 16 + m16) * DIM + kc * 32 + quad * 8;
        float4 f0 = *(const float4*)xp;
        float4 f1 = *(const float4*)(xp + 4);
        uint4 o;
        o.x = packbf(f0.x, f0.y); o.y = packbf(f0.z, f0.w);
        o.z = packbf(f1.x, f1.y); o.w = packbf(f1.z, f1.w);
        *(uint4*)(xbL + (size_t)t * 8) = o;
    }
}

// ---------------------------------------------------------------------------
// KV GEMM (bf16 MFMA) + RoPE on K.  grid = (512, 2), block = 256 (4 waves).
// blockIdx.y: 0 -> k, 1 -> v.  All fragment loads contiguous 1KB.
// k -> (B,H,S,16u32) packed stores; v -> fragment-linear vtL (kappa keys).
// ---------------------------------------------------------------------------
#define VSTU 68   // u32 stride of vs rows (64 rows: (h,m16) dim-pairs)
__global__ __launch_bounds__(256) void qkv_kernel(
    const unsigned short* __restrict__ xbL, const unsigned short* __restrict__ weffL,
    const float* __restrict__ tab,
    unsigned* __restrict__ kb, unsigned short* __restrict__ vtL)
{
    __shared__ unsigned vs_u[64 * VSTU];

    const int which = blockIdx.y + 1;         // 1=k, 2=v
    const unsigned short* W = weffL + which * DIM * DIM;

    const int tid = threadIdx.x;
    const int w = __builtin_amdgcn_readfirstlane(tid >> 6);
    const int lane = tid & 63;
    const int m16 = lane & 15, quad = lane >> 4;
    const int g = blockIdx.x * 4 + w;         // 16-token group
    const int b = g >> 4;

    short8 afrag[4];
#pragma unroll
    for (int kc = 0; kc < 4; kc++)
        afrag[kc] = *(const short8*)(xbL + ((size_t)(g * 4 + kc) * 64 + lane) * 8);

    floatx4 acc_e[NH], acc_o[NH];
#pragma unroll
    for (int h = 0; h < NH; h++) {
        acc_e[h] = (floatx4){0.f, 0.f, 0.f, 0.f};
        acc_o[h] = (floatx4){0.f, 0.f, 0.f, 0.f};
    }

#pragma unroll
    for (int kc = 0; kc < 4; kc++) {
#pragma unroll
        for (int h = 0; h < NH; h++) {
            const unsigned short* base = W + ((kc * 8 + h * 2) * 64 + lane) * 8;
            short8 be = *(const short8*)base;
            short8 bo = *(const short8*)(base + 512);
            acc_e[h] = __builtin_amdgcn_mfma_f32_16x16x32_bf16(afrag[kc], be, acc_e[h], 0, 0, 0);
            acc_o[h] = __builtin_amdgcn_mfma_f32_16x16x32_bf16(afrag[kc], bo, acc_o[h], 0, 0, 0);
        }
    }

    if (which == 1) {  // k: in-lane RoPE, packed uint stores (B,H,S,16)
        const int sposq = (g & 15) * 16 + quad * 4;
#pragma unroll
        for (int r = 0; r < 4; r++) {
            int spos = sposq + r;
            float2 cs = *(const float2*)(tab + ((size_t)spos * 16 + m16) * 2);
#pragma unroll
            for (int h = 0; h < NH; h++) {
                float e = acc_e[h][r], o = acc_o[h][r];
                kb[((size_t)(b * NH + h) * SEQ + spos) * (HD / 2) + m16] =
                    packbf(e * cs.x - o * cs.y, e * cs.y + o * cs.x);
            }
        }
    } else {
        // v: LDS rows = (h,m16) dim-pairs (u32), cols = kappa-permuted token
        // slots with XOR swizzle; then emit fragment-linear vtL.
        const int cloc = w >> 1;
        const int sig0 = (w & 1);
#pragma unroll
        for (int r = 0; r < 4; r++) {
            int sig = 8 * quad + 2 * r + sig0;          // kappa in 0..31
            int col = cloc * 32 + (sig ^ ((m16 & 3) << 3));
#pragma unroll
            for (int h = 0; h < NH; h++)
                vs_u[(h * 16 + m16) * VSTU + col] = packbf(acc_e[h][r], acc_o[h][r]);
        }
        __syncthreads();
        const int cb = ((blockIdx.x * 64) & 255) >> 5;   // chunk base
        const size_t bhbase = (size_t)(b * NH) * 8;
#pragma unroll
        for (int it = 0; it < 4; it++) {
            int f = it * 256 + tid;          // 0..1023
            int c_l = f >> 9;
            int h   = (f >> 7) & 3;
            int p   = (f >> 6) & 1;
            int ln  = f & 63;
            int fm16 = ln & 15, fq = ln >> 4;
            const unsigned* src = vs_u + (h * 16 + fm16) * VSTU + c_l * 32
                                + ((fq ^ (fm16 & 3)) * 8);
            uint4 a = *(const uint4*)src;
            uint4 bb = *(const uint4*)(src + 4);
            unsigned sel = p ? 0x07060302u : 0x05040100u;
            uint4 o;
            o.x = __builtin_amdgcn_perm(a.y,  a.x,  sel);
            o.y = __builtin_amdgcn_perm(a.w,  a.z,  sel);
            o.z = __builtin_amdgcn_perm(bb.y, bb.x, sel);
            o.w = __builtin_amdgcn_perm(bb.w, bb.z, sel);
            *(uint4*)(vtL + (((bhbase + h * 8 + cb + c_l) * 2 + p) * 512 + ln * 8)) = o;
        }
    }
}

// ---------------------------------------------------------------------------
// Fused Q-projection + attention + out-projection, causally balanced:
// grid = (4, 128); block processes qtile 7-p then p (uniform 9-chunk blocks).
// Wave = head, 32 queries.  Q computed in-prologue from xbL (8 MFMA + RoPE,
// staged through the P buffer -- same strides as the P path).  Max-free exp2
// softmax; ones-MFMA row sums; kappa-packed P; K/V prefetch.
// ---------------------------------------------------------------------------
#define PBU 20          // u32 stride (40 shorts = 80B rows, 16B-aligned)
#define OS_STRIDE 136
__global__ __launch_bounds__(256) void attn_kernel(
    const unsigned short* __restrict__ xbL, const unsigned short* __restrict__ weffL,
    const float* __restrict__ tab,
    const unsigned short* __restrict__ kbs, const unsigned short* __restrict__ vtL,
    float* __restrict__ out)
{
    __shared__ unsigned pbuf_u[4 * 2 * 16 * PBU];
    __shared__ unsigned short os[32 * OS_STRIDE];

    const int p  = blockIdx.x;           // 0..3
    const int b  = blockIdx.y;
    const int tid = threadIdx.x;
    const int w = __builtin_amdgcn_readfirstlane(tid >> 6);   // head
    const int lane = tid & 63;
    const int m16 = lane & 15, quad = lane >> 4;

    const size_t bh = (size_t)(b * NH + w);
    const unsigned short* krow = kbs + bh * SEQ * HD;
    const unsigned short* vbase = vtL + bh * 8 * 1024;
    const unsigned short* Wq = weffL;
    const unsigned short* woL = weffL + (size_t)3 * DIM * DIM;

    const short ob = (short)0x3F80;       // bf16 1.0
    const short8 bones = {ob, ob, ob, ob, ob, ob, ob, ob};
    const floatx4 z4 = (floatx4){0.f, 0.f, 0.f, 0.f};
    unsigned* pw = pbuf_u + (w * 2) * 16 * PBU;

    for (int half = 0; half < 2; half++) {
        const int qt = half ? p : (7 - p);     // heavy tile first
        const int q0 = qt * 32;

        // ---- Q prologue: project + RoPE + LDS transpose (P-buffer strides) ----
        short8 aq[2];
#pragma unroll
        for (int qs = 0; qs < 2; qs++) {
            const int g = b * 16 + qt * 2 + qs;
            floatx4 ae = z4, ao = z4;
#pragma unroll
            for (int kc = 0; kc < 4; kc++) {
                short8 xf = *(const short8*)(xbL + ((size_t)(g * 4 + kc) * 64 + lane) * 8);
                const unsigned short* bp = Wq + ((size_t)(kc * 8 + w * 2) * 64 + lane) * 8;
                ae = __builtin_amdgcn_mfma_f32_16x16x32_bf16(xf, *(const short8*)bp, ae, 0, 0, 0);
                ao = __builtin_amdgcn_mfma_f32_16x16x32_bf16(xf, *(const short8*)(bp + 512), ao, 0, 0, 0);
            }
            const int sbase = q0 + qs * 16 + quad * 4;
#pragma unroll
            for (int r = 0; r < 4; r++) {
                float2 cs = *(const float2*)(tab + ((size_t)(sbase + r) * 16 + m16) * 2);
                float e = ae[r], o = ao[r];
                pw[(quad * 4 + r) * PBU + m16] =
                    packbf(e * cs.x - o * cs.y, e * cs.y + o * cs.x);
            }
            aq[qs] = *(const short8*)((const unsigned short*)pw + m16 * (PBU * 2) + quad * 8);
        }

        floatx4 o_e[2], o_o[2], o_l[2];
#pragma unroll
        for (int qs = 0; qs < 2; qs++) { o_e[qs] = z4; o_o[qs] = z4; o_l[qs] = z4; }

        const int nchunks = qt + 1;
        short8 cbk0, cbk1, cbve, cbvo, nbk0, nbk1, nbve, nbvo;
        {
            cbk0 = *(const short8*)(krow + (size_t)m16 * HD + quad * 8);
            cbk1 = *(const short8*)(krow + (size_t)(16 + m16) * HD + quad * 8);
            const unsigned short* vp = vbase + lane * 8;
            cbve = *(const short8*)vp;
            cbvo = *(const short8*)(vp + 512);
        }

        for (int c = 0; c < nchunks; c++) {
            const int cn = (c + 1 < nchunks) ? c + 1 : c;
            {
                const unsigned short* kp = krow + (size_t)cn * 32 * HD;
                nbk0 = *(const short8*)(kp + (size_t)m16 * HD + quad * 8);
                nbk1 = *(const short8*)(kp + (size_t)(16 + m16) * HD + quad * 8);
                const unsigned short* vp = vbase + (size_t)cn * 1024 + lane * 8;
                nbve = *(const short8*)vp;
                nbvo = *(const short8*)(vp + 512);
            }
            const int k0 = c * 32;
            const int kg0 = k0 + m16, kg1 = k0 + 16 + m16;
#pragma unroll
            for (int qs = 0; qs < 2; qs++) {
                floatx4 s0 = __builtin_amdgcn_mfma_f32_16x16x32_bf16(aq[qs], cbk0, z4, 0, 0, 0);
                floatx4 s1 = __builtin_amdgcn_mfma_f32_16x16x32_bf16(aq[qs], cbk1, z4, 0, 0, 0);
                unsigned* pq = pw + qs * 16 * PBU;
                const int qg = q0 + qs * 16 + quad * 4;
#pragma unroll
                for (int r = 0; r < 4; r++) {
                    float p0 = (kg0 <= qg + r) ? EXP2F(s0[r]) : 0.f;
                    float p1 = (kg1 <= qg + r) ? EXP2F(s1[r]) : 0.f;
                    pq[(quad * 4 + r) * PBU + m16] = packbf(p0, p1);  // kappa=2*m16+t
                }
                const unsigned short* pqs = (const unsigned short*)pq;
                short8 ap = *(const short8*)(pqs + m16 * (PBU * 2) + quad * 8);
                o_e[qs] = __builtin_amdgcn_mfma_f32_16x16x32_bf16(ap, cbve, o_e[qs], 0, 0, 0);
                o_o[qs] = __builtin_amdgcn_mfma_f32_16x16x32_bf16(ap, cbvo, o_o[qs], 0, 0, 0);
                o_l[qs] = __builtin_amdgcn_mfma_f32_16x16x32_bf16(ap, bones, o_l[qs], 0, 0, 0);
            }
            cbk0 = nbk0; cbk1 = nbk1; cbve = nbve; cbvo = nbvo;
        }

        if (half) __syncthreads();        // os reuse: wait for half-0 reads
        unsigned* osu = (unsigned*)os;
#pragma unroll
        for (int qs = 0; qs < 2; qs++)
#pragma unroll
            for (int r = 0; r < 4; r++) {
                float inv = 1.f / o_l[qs][r];
                osu[(qs * 16 + quad * 4 + r) * (OS_STRIDE / 2) + w * 16 + m16] =
                    packbf(o_e[qs][r] * inv, o_o[qs][r] * inv);
            }
        __syncthreads();

        // out-projection: wave w -> tokens (w&1)*16.., dims (w>>1)*64..
        const int tw = (w & 1) * 16;
        const int dbase = (w >> 1) * 64;

        short8 af[4];
#pragma unroll
        for (int kc = 0; kc < 4; kc++)
            af[kc] = *(const short8*)(os + (tw + m16) * OS_STRIDE + kc * 32 + quad * 8);

        floatx4 acc[4];
#pragma unroll
        for (int nt = 0; nt < 4; nt++) acc[nt] = z4;
#pragma unroll
        for (int kc = 0; kc < 4; kc++)
#pragma unroll
            for (int nt = 0; nt < 4; nt++) {
                short8 bf = *(const short8*)(woL + ((kc * 8 + (w >> 1) * 4 + nt) * 64 + lane) * 8);
                acc[nt] = __builtin_amdgcn_mfma_f32_16x16x32_bf16(af[kc], bf, acc[nt], 0, 0, 0);
            }

#pragma unroll
        for (int nt = 0; nt < 4; nt++)
#pragma unroll
            for (int r = 0; r < 4; r++)
                out[(size_t)(b * SEQ + q0 + tw + quad * 4 + r) * DIM
                    + dbase + nt * 16 + m16] = acc[nt][r];
    }
}

extern "C" void kernel_launch(void* const* d_in, const int* in_sizes, int n_in,
                              void* d_out, int out_size, void* d_ws, size_t ws_size,
                              hipStream_t stream)
{
    const float* x  = (const float*)d_in[0];
    const float* wq = (const float*)d_in[1];
    const float* wk = (const float*)d_in[2];
    const float* wv = (const float*)d_in[3];
    const float* wo = (const float*)d_in[4];
    const float* Aq = (const float*)d_in[5];
    const float* Bq = (const float*)d_in[6];
    const float* Ak = (const float*)d_in[7];
    const float* Bk = (const float*)d_in[8];
    const float* Av = (const float*)d_in[9];
    const float* Bv = (const float*)d_in[10];
    float* out = (float*)d_out;
    char* ws = (char*)d_ws;

    unsigned*       kb    = (unsigned*)(ws + KB_OFF);
    unsigned short* vtL   = (unsigned short*)(ws + VT_OFF);
    unsigned short* xbL   = (unsigned short*)(ws + XB_OFF);
    unsigned short* weffL = (unsigned short*)(ws + WE_OFF);
    float*          tab   = (float*)(ws + TAB_OFF);

    prep_kernel<<<144 + 2048, 256, 0, stream>>>(
        x, wq, wk, wv, wo, Aq, Bq, Ak, Bk, Av, Bv, weffL, tab, xbL);
    qkv_kernel<<<dim3(BS / 64, 2), 256, 0, stream>>>(xbL, weffL, tab, kb, vtL);
    attn_kernel<<<dim3(4, BATCH), 256, 0, stream>>>(
        xbL, weffL, tab, (const unsigned short*)kb, vtL, out);
}

// Round 11
// 117.180 us; speedup vs baseline: 1.0211x; 1.0211x over previous
//
#include <hip/hip_runtime.h>
#include <math.h>

typedef __attribute__((ext_vector_type(8))) short short8;
typedef __attribute__((ext_vector_type(4))) float floatx4;

#define NH 4
#define HD 32
#define DIM 128
#define SEQ 256
#define BATCH 128
#define BS (BATCH*SEQ)
#define RANK 8
#define SCALING 2.0f
#define INV_SQRT_HD 0.17677669529663687f
#define LOG2E 1.4426950408889634f

#if __has_builtin(__builtin_amdgcn_exp2f)
#define EXP2F __builtin_amdgcn_exp2f
#else
#define EXP2F exp2f
#endif

// workspace byte offsets
#define QB_OFF  (0ull)
#define KB_OFF  (8ull<<20)
#define VT_OFF  (16ull<<20)   // V fragment-linear (b,h,chunk,parity), kappa-permuted keys
#define XB_OFF  (24ull<<20)   // x bf16, fragment-linear
#define WE_OFF  (32ull<<20)   // 4 x 128x128 bf16 weights, fragment-linear
#define TAB_OFF (33ull<<20)   // 256x16 float2 (cos,sin)

static __device__ __forceinline__ unsigned short f2bf(float f) {
    unsigned u = __float_as_uint(f);
    return (unsigned short)((u + 0x7FFFu + ((u >> 16) & 1u)) >> 16);
}
// RNE bf16 pair pack: 2 add-chains + 1 v_perm_b32
static __device__ __forceinline__ unsigned packbf(float lo, float hi) {
    unsigned ua = __float_as_uint(lo), ub = __float_as_uint(hi);
    ua += 0x7FFFu + ((ua >> 16) & 1u);
    ub += 0x7FFFu + ((ub >> 16) & 1u);
    return __builtin_amdgcn_perm(ub, ua, 0x07060302);  // (hi16(ub)<<16)|hi16(ua)
}

// ---------------------------------------------------------------------------
// prep: fragment-linear weights (LoRA folded; q gets 1/sqrt(hd)*log2e),
// RoPE table, x -> bf16 fragment-linear.  grid = 128 + 16 + 2048.
// W-section: one u32 (2 bf16) per thread for full-CU parallelism.
// ---------------------------------------------------------------------------
__global__ __launch_bounds__(256) void prep_kernel(
    const float* __restrict__ x,
    const float* __restrict__ wq, const float* __restrict__ wk,
    const float* __restrict__ wv, const float* __restrict__ wo,
    const float* __restrict__ Aq, const float* __restrict__ Bq,
    const float* __restrict__ Ak, const float* __restrict__ Bk,
    const float* __restrict__ Av, const float* __restrict__ Bv,
    unsigned short* __restrict__ weffL, float* __restrict__ tab,
    unsigned short* __restrict__ xbL)
{
    const int bid = blockIdx.x, tid = threadIdx.x;
    if (bid < 128) {
        int t = bid * 256 + tid;            // u32 index 0..32767
        int m    = t >> 13;
        int kc   = (t >> 11) & 3;
        int s    = (t >> 8) & 7;
        int lane = (t >> 2) & 63;
        int e    = t & 3;                   // u32 within fragment
        int m16 = lane & 15, quad = lane >> 4;
        int row = (m < 3) ? ((s >> 1) * 32 + 2 * m16 + (s & 1)) : (s * 16 + m16);
        int col = kc * 32 + quad * 8 + 2 * e;
        const float* W = m == 0 ? wq : (m == 1 ? wk : (m == 2 ? wv : wo));
        const float* A  = m == 0 ? Aq : (m == 1 ? Ak : Av);
        const float* Bm = m == 0 ? Bq : (m == 1 ? Bk : Bv);
        float v0 = W[row * DIM + col], v1 = W[row * DIM + col + 1];
        if (m < 3) {
            float s0 = 0.f, s1 = 0.f;
#pragma unroll
            for (int r = 0; r < RANK; r++) {
                float br = Bm[row * RANK + r];
                s0 += br * A[r * DIM + col];
                s1 += br * A[r * DIM + col + 1];
            }
            v0 += SCALING * s0;
            v1 += SCALING * s1;
        }
        if (m == 0) { v0 *= INV_SQRT_HD * LOG2E; v1 *= INV_SQRT_HD * LOG2E; }
        ((unsigned*)weffL)[t] = packbf(v0, v1);
    } else if (bid < 144) {
        int gid = (bid - 128) * 256 + tid;  // 0..4095
        int spos = gid >> 4, i = gid & 15;
        float invf = exp2f(-0.83048202f * (float)i);  // 10000^(-i/16)
        float ang = (float)spos * invf;
        float c, s;
        sincosf(ang, &s, &c);
        tab[gid * 2]     = c;
        tab[gid * 2 + 1] = s;
    } else {
        int t = (bid - 144) * 256 + tid;    // 0..524287
        int g    = t >> 8;
        int kc   = (t >> 6) & 3;
        int lane = t & 63;
        int m16 = lane & 15, quad = lane >> 4;
        const float* xp = x + (size_t)(g * 16 + m16) * DIM + kc * 32 + quad * 8;
        float4 f0 = *(const float4*)xp;
        float4 f1 = *(const float4*)(xp + 4);
        uint4 o;
        o.x = packbf(f0.x, f0.y); o.y = packbf(f0.z, f0.w);
        o.z = packbf(f1.x, f1.y); o.w = packbf(f1.z, f1.w);
        *(uint4*)(xbL + (size_t)t * 8) = o;
    }
}

// ---------------------------------------------------------------------------
// QKV GEMM (bf16 MFMA) + RoPE.  grid = (512, 3), block = 256 (4 waves).
// All fragment loads contiguous 1KB.  q,k -> (B,H,S,16u32) packed stores.
// v -> fragment-linear vtL with kappa-permuted keys (kappa = 2*m16 + t):
// u32 dim-pair LDS rows + XOR-swizzled columns -> b128 reads + v_perm split.
// ---------------------------------------------------------------------------
#define VSTU 68   // u32 stride of vs rows (64 rows: (h,m16) dim-pairs)
__global__ __launch_bounds__(256) void qkv_kernel(
    const unsigned short* __restrict__ xbL, const unsigned short* __restrict__ weffL,
    const float* __restrict__ tab,
    unsigned* __restrict__ qb, unsigned* __restrict__ kb,
    unsigned short* __restrict__ vtL)
{
    __shared__ unsigned vs_u[64 * VSTU];

    const int which = blockIdx.y;
    const unsigned short* W = weffL + which * DIM * DIM;

    const int tid = threadIdx.x;
    const int w = __builtin_amdgcn_readfirstlane(tid >> 6);
    const int lane = tid & 63;
    const int m16 = lane & 15, quad = lane >> 4;
    const int g = blockIdx.x * 4 + w;         // 16-token group
    const int b = g >> 4;

    short8 afrag[4];
#pragma unroll
    for (int kc = 0; kc < 4; kc++)
        afrag[kc] = *(const short8*)(xbL + ((size_t)(g * 4 + kc) * 64 + lane) * 8);

    floatx4 acc_e[NH], acc_o[NH];
#pragma unroll
    for (int h = 0; h < NH; h++) {
        acc_e[h] = (floatx4){0.f, 0.f, 0.f, 0.f};
        acc_o[h] = (floatx4){0.f, 0.f, 0.f, 0.f};
    }

#pragma unroll
    for (int kc = 0; kc < 4; kc++) {
#pragma unroll
        for (int h = 0; h < NH; h++) {
            const unsigned short* base = W + ((kc * 8 + h * 2) * 64 + lane) * 8;
            short8 be = *(const short8*)base;
            short8 bo = *(const short8*)(base + 512);
            acc_e[h] = __builtin_amdgcn_mfma_f32_16x16x32_bf16(afrag[kc], be, acc_e[h], 0, 0, 0);
            acc_o[h] = __builtin_amdgcn_mfma_f32_16x16x32_bf16(afrag[kc], bo, acc_o[h], 0, 0, 0);
        }
    }

    if (which < 2) {   // q/k: in-lane RoPE, packed uint stores (B,H,S,16)
        unsigned* outp = which == 0 ? qb : kb;
        const int sposq = (g & 15) * 16 + quad * 4;
#pragma unroll
        for (int r = 0; r < 4; r++) {
            int spos = sposq + r;
            float2 cs = *(const float2*)(tab + ((size_t)spos * 16 + m16) * 2);
#pragma unroll
            for (int h = 0; h < NH; h++) {
                float e = acc_e[h][r], o = acc_o[h][r];
                outp[((size_t)(b * NH + h) * SEQ + spos) * (HD / 2) + m16] =
                    packbf(e * cs.x - o * cs.y, e * cs.y + o * cs.x);
            }
        }
    } else {
        // v: LDS rows = (h,m16) dim-pairs (u32), cols = kappa-permuted token
        // slots with XOR swizzle; then emit fragment-linear vtL.
        const int cloc = w >> 1;
        const int sig0 = (w & 1);
#pragma unroll
        for (int r = 0; r < 4; r++) {
            int sig = 8 * quad + 2 * r + sig0;          // kappa in 0..31
            int col = cloc * 32 + (sig ^ ((m16 & 3) << 3));
#pragma unroll
            for (int h = 0; h < NH; h++)
                vs_u[(h * 16 + m16) * VSTU + col] = packbf(acc_e[h][r], acc_o[h][r]);
        }
        __syncthreads();
        const int cb = ((blockIdx.x * 64) & 255) >> 5;   // chunk base
        const size_t bhbase = (size_t)(b * NH) * 8;
#pragma unroll
        for (int it = 0; it < 4; it++) {
            int f = it * 256 + tid;          // 0..1023
            int c_l = f >> 9;
            int h   = (f >> 7) & 3;
            int p   = (f >> 6) & 1;
            int ln  = f & 63;
            int fm16 = ln & 15, fq = ln >> 4;
            const unsigned* src = vs_u + (h * 16 + fm16) * VSTU + c_l * 32
                                + ((fq ^ (fm16 & 3)) * 8);
            uint4 a = *(const uint4*)src;
            uint4 bb = *(const uint4*)(src + 4);
            unsigned sel = p ? 0x07060302u : 0x05040100u;
            uint4 o;
            o.x = __builtin_amdgcn_perm(a.y,  a.x,  sel);
            o.y = __builtin_amdgcn_perm(a.w,  a.z,  sel);
            o.z = __builtin_amdgcn_perm(bb.y, bb.x, sel);
            o.w = __builtin_amdgcn_perm(bb.w, bb.z, sel);
            *(uint4*)(vtL + (((bhbase + h * 8 + cb + c_l) * 2 + p) * 512 + ln * 8)) = o;
        }
    }
}

// ---------------------------------------------------------------------------
// Fused attention + out-projection, causally BALANCED: grid = (4, 128),
// block = 256; each block processes qtile 7-p then qtile p (uniform 9-chunk
// blocks -> no idle tail).  Wave = head, 32 queries.  Max-free exp2 softmax;
// ones-MFMA row sums; kappa-packed P; K/V prefetch.
// ---------------------------------------------------------------------------
#define PBU 20          // u32 stride (40 shorts = 80B rows, 16B-aligned)
#define OS_STRIDE 136
__global__ __launch_bounds__(256) void attn_kernel(
    const unsigned short* __restrict__ qbs, const unsigned short* __restrict__ kbs,
    const unsigned short* __restrict__ vtL, const unsigned short* __restrict__ woL,
    float* __restrict__ out)
{
    __shared__ unsigned pbuf_u[4 * 2 * 16 * PBU];
    __shared__ unsigned short os[32 * OS_STRIDE];

    const int p  = blockIdx.x;           // 0..3
    const int b  = blockIdx.y;
    const int tid = threadIdx.x;
    const int w = __builtin_amdgcn_readfirstlane(tid >> 6);   // head
    const int lane = tid & 63;
    const int m16 = lane & 15, quad = lane >> 4;

    const size_t bh = (size_t)(b * NH + w);
    const unsigned short* krow = kbs + bh * SEQ * HD;
    const unsigned short* vbase = vtL + bh * 8 * 1024;

    const short ob = (short)0x3F80;       // bf16 1.0
    const short8 bones = {ob, ob, ob, ob, ob, ob, ob, ob};
    const floatx4 z4 = (floatx4){0.f, 0.f, 0.f, 0.f};
    unsigned* pw = pbuf_u + (w * 2) * 16 * PBU;

    for (int half = 0; half < 2; half++) {
        const int qt = half ? p : (7 - p);     // heavy tile first
        const int q0 = qt * 32;
        const unsigned short* qrow = qbs + (bh * SEQ + q0) * HD;

        short8 aq[2];
#pragma unroll
        for (int qs = 0; qs < 2; qs++)
            aq[qs] = *(const short8*)(qrow + (size_t)(qs * 16 + m16) * HD + quad * 8);

        floatx4 o_e[2], o_o[2], o_l[2];
#pragma unroll
        for (int qs = 0; qs < 2; qs++) { o_e[qs] = z4; o_o[qs] = z4; o_l[qs] = z4; }

        const int nchunks = qt + 1;
        short8 cbk0, cbk1, cbve, cbvo, nbk0, nbk1, nbve, nbvo;
        {
            cbk0 = *(const short8*)(krow + (size_t)m16 * HD + quad * 8);
            cbk1 = *(const short8*)(krow + (size_t)(16 + m16) * HD + quad * 8);
            const unsigned short* vp = vbase + lane * 8;
            cbve = *(const short8*)vp;
            cbvo = *(const short8*)(vp + 512);
        }

        for (int c = 0; c < nchunks; c++) {
            const int cn = (c + 1 < nchunks) ? c + 1 : c;
            {
                const unsigned short* kp = krow + (size_t)cn * 32 * HD;
                nbk0 = *(const short8*)(kp + (size_t)m16 * HD + quad * 8);
                nbk1 = *(const short8*)(kp + (size_t)(16 + m16) * HD + quad * 8);
                const unsigned short* vp = vbase + (size_t)cn * 1024 + lane * 8;
                nbve = *(const short8*)vp;
                nbvo = *(const short8*)(vp + 512);
            }
            const int k0 = c * 32;
            const int kg0 = k0 + m16, kg1 = k0 + 16 + m16;
#pragma unroll
            for (int qs = 0; qs < 2; qs++) {
                floatx4 s0 = __builtin_amdgcn_mfma_f32_16x16x32_bf16(aq[qs], cbk0, z4, 0, 0, 0);
                floatx4 s1 = __builtin_amdgcn_mfma_f32_16x16x32_bf16(aq[qs], cbk1, z4, 0, 0, 0);
                unsigned* pq = pw + qs * 16 * PBU;
                const int qg = q0 + qs * 16 + quad * 4;
#pragma unroll
                for (int r = 0; r < 4; r++) {
                    float p0 = (kg0 <= qg + r) ? EXP2F(s0[r]) : 0.f;
                    float p1 = (kg1 <= qg + r) ? EXP2F(s1[r]) : 0.f;
                    pq[(quad * 4 + r) * PBU + m16] = packbf(p0, p1);  // kappa=2*m16+t
                }
                const unsigned short* pqs = (const unsigned short*)pq;
                short8 ap = *(const short8*)(pqs + m16 * (PBU * 2) + quad * 8);
                o_e[qs] = __builtin_amdgcn_mfma_f32_16x16x32_bf16(ap, cbve, o_e[qs], 0, 0, 0);
                o_o[qs] = __builtin_amdgcn_mfma_f32_16x16x32_bf16(ap, cbvo, o_o[qs], 0, 0, 0);
                o_l[qs] = __builtin_amdgcn_mfma_f32_16x16x32_bf16(ap, bones, o_l[qs], 0, 0, 0);
            }
            cbk0 = nbk0; cbk1 = nbk1; cbve = nbve; cbvo = nbvo;
        }

        if (half) __syncthreads();        // os reuse: wait for half-0 reads
        unsigned* osu = (unsigned*)os;
#pragma unroll
        for (int qs = 0; qs < 2; qs++)
#pragma unroll
            for (int r = 0; r < 4; r++) {
                float inv = 1.f / o_l[qs][r];
                osu[(qs * 16 + quad * 4 + r) * (OS_STRIDE / 2) + w * 16 + m16] =
                    packbf(o_e[qs][r] * inv, o_o[qs][r] * inv);
            }
        __syncthreads();

        // out-projection: wave w -> tokens (w&1)*16.., dims (w>>1)*64..
        const int tw = (w & 1) * 16;
        const int dbase = (w >> 1) * 64;

        short8 af[4];
#pragma unroll
        for (int kc = 0; kc < 4; kc++)
            af[kc] = *(const short8*)(os + (tw + m16) * OS_STRIDE + kc * 32 + quad * 8);

        floatx4 acc[4];
#pragma unroll
        for (int nt = 0; nt < 4; nt++) acc[nt] = z4;
#pragma unroll
        for (int kc = 0; kc < 4; kc++)
#pragma unroll
            for (int nt = 0; nt < 4; nt++) {
                short8 bf = *(const short8*)(woL + ((kc * 8 + (w >> 1) * 4 + nt) * 64 + lane) * 8);
                acc[nt] = __builtin_amdgcn_mfma_f32_16x16x32_bf16(af[kc], bf, acc[nt], 0, 0, 0);
            }

#pragma unroll
        for (int nt = 0; nt < 4; nt++)
#pragma unroll
            for (int r = 0; r < 4; r++)
                out[(size_t)(b * SEQ + q0 + tw + quad * 4 + r) * DIM
                    + dbase + nt * 16 + m16] = acc[nt][r];
    }
}

extern "C" void kernel_launch(void* const* d_in, const int* in_sizes, int n_in,
                              void* d_out, int out_size, void* d_ws, size_t ws_size,
                              hipStream_t stream)
{
    const float* x  = (const float*)d_in[0];
    const float* wq = (const float*)d_in[1];
    const float* wk = (const float*)d_in[2];
    const float* wv = (const float*)d_in[3];
    const float* wo = (const float*)d_in[4];
    const float* Aq = (const float*)d_in[5];
    const float* Bq = (const float*)d_in[6];
    const float* Ak = (const float*)d_in[7];
    const float* Bk = (const float*)d_in[8];
    const float* Av = (const float*)d_in[9];
    const float* Bv = (const float*)d_in[10];
    float* out = (float*)d_out;
    char* ws = (char*)d_ws;

    unsigned*       qb    = (unsigned*)(ws + QB_OFF);
    unsigned*       kb    = (unsigned*)(ws + KB_OFF);
    unsigned short* vtL   = (unsigned short*)(ws + VT_OFF);
    unsigned short* xbL   = (unsigned short*)(ws + XB_OFF);
    unsigned short* weffL = (unsigned short*)(ws + WE_OFF);
    float*          tab   = (float*)(ws + TAB_OFF);

    prep_kernel<<<144 + 2048, 256, 0, stream>>>(
        x, wq, wk, wv, wo, Aq, Bq, Ak, Bk, Av, Bv, weffL, tab, xbL);
    qkv_kernel<<<dim3(BS / 64, 3), 256, 0, stream>>>(xbL, weffL, tab, qb, kb, vtL);
    attn_kernel<<<dim3(4, BATCH), 256, 0, stream>>>(
        (const unsigned short*)qb, (const unsigned short*)kb, vtL,
        weffL + 3 * DIM * DIM, out);
}